// Round 4
// baseline (172.261 us; speedup 1.0000x reference)
//
#include <hip/hip_runtime.h>
#include <math.h>

// VQ-VAE quantizer, MI355X. N=65536 vectors (B64*H32*W32), D=64, K=1024.
// Round-4 structure: register-tiled fp32 GEMM (this is (N,64)x(64,K) + argmin).
//  - block = 256 thr = 16 k-groups x 16 v-groups; tile 64 vectors x 128-code chunks
//  - LDS: z^T [64d][64v] (16KB) + XOR-swizzled c [128k][16 d-quads] (32KB)
//  - thread: acc[4v][8k]; per d-quad 12 ds_read_b128 : 128 fmaf  (~11:1)
//  - argmin via packed u64 (dist_bits<<32)|k + LDS atomicMin: order-independent,
//    ties -> smaller k == jnp.argmin first-occurrence. dist formula unchanged
//    from rounds 1-3 (passed): fl(fl(zz+cc) - fl(2*dot)).
// Rounds 1-3 evidence: per-lane-z + SGPR codebook row serializes on s_load
// (SGPR file can't hold 2 rows) -> VALUBusy pinned ~47%. This kernel feeds
// FMAs from LDS with register double-buffering headroom instead.

#define OFF_VQLOSS  4194304
#define OFF_COMMIT  4194305
#define OFF_IDX     4194306
#define OFF_USAGE   4259842
#define OFF_PERP    4259843

__global__ __launch_bounds__(256) void vq_init(const float* __restrict__ cb,
                                               float* __restrict__ ws_f,
                                               unsigned* __restrict__ ws_u) {
    int k = blockIdx.x * 256 + threadIdx.x;   // grid = 4 x 256 -> k in [0,1024)
    ws_u[1024 + k] = 0u;                       // zero histogram every launch
    const float* row = cb + k * 64;
    float acc = 0.0f;
    #pragma unroll
    for (int d = 0; d < 64; ++d) {
        float v = row[d];
        acc = __fadd_rn(acc, __fmul_rn(v, v)); // mul-then-add, mimic jnp.sum(c*c)
    }
    ws_f[k] = acc;
}

__global__ __launch_bounds__(256, 3) void vq_main(const float* __restrict__ ze,
                                                  const float* __restrict__ cb,
                                                  const float* __restrict__ cc,
                                                  unsigned* __restrict__ hist,
                                                  float* __restrict__ partial,
                                                  float* __restrict__ out) {
    const int t  = threadIdx.x;
    const int kg = t & 15;        // k-group: codes kg*8..kg*8+7 within chunk
    const int vg = t >> 4;        // v-group: vectors vg*4..vg*4+3
    const int blk = blockIdx.x;   // 1024 blocks x 64 vectors
    const int b   = blk >> 4;
    const int hw0 = (blk & 15) << 6;
    const size_t zbase = ((size_t)b << 16) + (size_t)hw0; // ze[(b,d,hw)] = zbase + d*1024 + v

    __shared__ float zt[64 * 64];              // [d][v]
    __shared__ float ct[128 * 64];             // quad layout: kl*16 + (dq ^ (kl>>3))
    __shared__ unsigned long long best[64];    // packed (dist_bits<<32)|k per vector

    // ---- stage z^T tile (coalesced: consecutive t -> consecutive v) ----
    #pragma unroll
    for (int rep = 0; rep < 4; ++rep) {
        int idx4 = rep * 256 + t;              // over 64d x 16 v-quads
        int d = idx4 >> 4, vq = idx4 & 15;
        float4 v4 = *reinterpret_cast<const float4*>(ze + zbase + ((size_t)d << 10) + (vq << 2));
        *reinterpret_cast<float4*>(&zt[(d << 6) + (vq << 2)]) = v4;
    }
    if (t < 64) best[t] = ~0ull;
    __syncthreads();

    // ---- zz per owned vector: ascending-d mul-then-add chain (= jnp.sum(z*z)) ----
    float zzv[4] = {0.f, 0.f, 0.f, 0.f};
    for (int d = 0; d < 64; ++d) {
        float4 zq = *reinterpret_cast<const float4*>(&zt[(d << 6) + (vg << 2)]);
        zzv[0] = __fadd_rn(zzv[0], __fmul_rn(zq.x, zq.x));
        zzv[1] = __fadd_rn(zzv[1], __fmul_rn(zq.y, zq.y));
        zzv[2] = __fadd_rn(zzv[2], __fmul_rn(zq.z, zq.z));
        zzv[3] = __fadd_rn(zzv[3], __fmul_rn(zq.w, zq.w));
    }

    // ---- K loop: 8 chunks of 128 codes ----
    for (int ch = 0; ch < 8; ++ch) {
        const int c0 = ch << 7;
        // stage chunk: read cb[k][d] coalesced, ds_write XOR-swizzled quads
        #pragma unroll
        for (int rep = 0; rep < 8; ++rep) {
            int idx4 = rep * 256 + t;          // over 128k x 16 d-quads
            int kl = idx4 >> 4, dq = idx4 & 15;
            float4 c4 = *reinterpret_cast<const float4*>(cb + (((size_t)(c0 + kl)) << 6) + (dq << 2));
            *reinterpret_cast<float4*>(&ct[((kl << 4) + (dq ^ (kl >> 3))) << 2]) = c4;
        }
        __syncthreads();

        float acc[4][8];
        #pragma unroll
        for (int v = 0; v < 4; ++v)
            #pragma unroll
            for (int j = 0; j < 8; ++j) acc[v][j] = 0.0f;

        for (int dq = 0; dq < 16; ++dq) {
            // z: 4 d-rows of this thread's 4 vectors (broadcast, conflict-free)
            float zv[4][4];
            #pragma unroll
            for (int dd = 0; dd < 4; ++dd) {
                float4 zq = *reinterpret_cast<const float4*>(&zt[(((dq << 2) + dd) << 6) + (vg << 2)]);
                zv[dd][0] = zq.x; zv[dd][1] = zq.y; zv[dd][2] = zq.z; zv[dd][3] = zq.w;
            }
            // c: 8 code rows at this d-quad (swizzled -> 2-way banks, free)
            float cq[8][4];
            #pragma unroll
            for (int j = 0; j < 8; ++j) {
                int kl = (kg << 3) + j;
                float4 c4 = *reinterpret_cast<const float4*>(&ct[((kl << 4) + (dq ^ kg)) << 2]);
                cq[j][0] = c4.x; cq[j][1] = c4.y; cq[j][2] = c4.z; cq[j][3] = c4.w;
            }
            // 128 FMAs; per (v,j) accumulation is ascending-d
            #pragma unroll
            for (int j = 0; j < 8; ++j)
                #pragma unroll
                for (int dd = 0; dd < 4; ++dd)
                    #pragma unroll
                    for (int v = 0; v < 4; ++v)
                        acc[v][j] = fmaf(zv[dd][v], cq[j][dd], acc[v][j]);
        }

        // distances + order-independent packed argmin
        float ccj[8];
        #pragma unroll
        for (int j = 0; j < 8; ++j) ccj[j] = cc[c0 + (kg << 3) + j];
        #pragma unroll
        for (int v = 0; v < 4; ++v) {
            float bd = INFINITY; int bk = 0;
            #pragma unroll
            for (int j = 0; j < 8; ++j) {
                // dist = (zz + cc[k]) - 2*dot   (bit-identical formula to R1-3)
                float dist = __fsub_rn(__fadd_rn(zzv[v], ccj[j]),
                                       __fmul_rn(2.0f, acc[v][j]));
                if (dist < bd) { bd = dist; bk = c0 + (kg << 3) + j; }
            }
            unsigned long long pk =
                ((unsigned long long)__float_as_uint(bd) << 32) | (unsigned)bk;
            atomicMin(&best[(vg << 2) + v], pk);   // dist>0 -> bits monotone;
        }                                          // tie -> smaller k (argmin rule)
        __syncthreads();   // atomics done + ct reads done before restage
    }

    // ---- epilogue: wave 0, lane = vector ----
    if (t < 64) {
        const int v = t;
        const int bk = (int)(best[v] & 0xFFFFFFFFull);
        out[OFF_IDX + (blk << 6) + v] = (float)bk;
        atomicAdd(&hist[bk], 1u);                  // integer atomic: deterministic
        const float4* qrow = reinterpret_cast<const float4*>(cb + ((size_t)bk << 6));
        float sq = 0.0f;
        #pragma unroll
        for (int j = 0; j < 16; ++j) {
            float4 q4 = qrow[j];                   // divergent gather, L2-resident
            const float qa[4] = {q4.x, q4.y, q4.z, q4.w};
            #pragma unroll
            for (int e = 0; e < 4; ++e) {
                int d = 4 * j + e;
                out[zbase + ((size_t)d << 10) + v] = qa[e];  // z_q_st == z_q
                float diff = __fsub_rn(qa[e], zt[(d << 6) + v]);
                sq = __fadd_rn(sq, __fmul_rn(diff, diff));
            }
        }
        #pragma unroll
        for (int off = 32; off > 0; off >>= 1) sq += __shfl_down(sq, off, 64);
        if (t == 0) partial[blk] = sq;
    }
}

__global__ __launch_bounds__(256) void vq_fin(const float* __restrict__ partial,
                                              const unsigned* __restrict__ hist,
                                              float* __restrict__ out) {
    const int t = threadIdx.x;
    const int wid = t >> 6, lane = t & 63;
    __shared__ float s_loss[4], s_ent[4], s_nz[4];

    float v = 0.0f, ent = 0.0f, nz = 0.0f;
    #pragma unroll
    for (int i = 0; i < 4; ++i) {
        v += partial[t + 256 * i];                 // 1024 block partials
        unsigned c = hist[t + 256 * i];
        float p = (float)c * (1.0f / 65536.0f);    // exact (pow2 divide)
        ent += p * logf(p + 1e-10f);               // c==0 -> 0 * log(1e-10) = 0
        if (c > 0u) nz += 1.0f;
    }
    #pragma unroll
    for (int off = 32; off > 0; off >>= 1) {
        v   += __shfl_down(v,   off, 64);
        ent += __shfl_down(ent, off, 64);
        nz  += __shfl_down(nz,  off, 64);
    }
    if (lane == 0) { s_loss[wid] = v; s_ent[wid] = ent; s_nz[wid] = nz; }
    __syncthreads();
    if (t == 0) {
        float S  = (s_loss[0] + s_loss[1]) + (s_loss[2] + s_loss[3]);
        float vq = S * (1.0f / 4194304.0f);        // mean over B*D*H*W
        out[OFF_VQLOSS] = vq;
        out[OFF_COMMIT] = 0.25f * vq;              // BETA * same mean
        float E  = (s_ent[0] + s_ent[1]) + (s_ent[2] + s_ent[3]);
        float NZ = (s_nz[0] + s_nz[1]) + (s_nz[2] + s_nz[3]);
        out[OFF_USAGE] = NZ * (1.0f / 1024.0f);
        out[OFF_PERP]  = expf(-E);
    }
}

extern "C" void kernel_launch(void* const* d_in, const int* in_sizes, int n_in,
                              void* d_out, int out_size, void* d_ws, size_t ws_size,
                              hipStream_t stream) {
    const float* ze = (const float*)d_in[0];
    const float* cb = (const float*)d_in[1];
    float*    out  = (float*)d_out;
    float*    ws_f = (float*)d_ws;
    unsigned* ws_u = (unsigned*)d_ws;

    vq_init<<<dim3(4),    dim3(256), 0, stream>>>(cb, ws_f, ws_u);
    vq_main<<<dim3(1024), dim3(256), 0, stream>>>(ze, cb, ws_f, ws_u + 1024,
                                                  ws_f + 2048, out);
    vq_fin <<<dim3(1),    dim3(256), 0, stream>>>(ws_f + 2048, ws_u + 1024, out);
}

// Round 5
// 98.170 us; speedup vs baseline: 1.7547x; 1.7547x over previous
//
#include <hip/hip_runtime.h>
#include <math.h>

// VQ-VAE quantizer, MI355X. N=65536 vectors (B64*H32*W32), D=64, K=1024.
// Round-5: bf16x3-split MFMA GEMM (CDNA4 has no fp32 MFMA; fp32-VALU floor is
// ~55us pure-FMA and rounds 1-4 plateaued at ~3x that). dot computed as 8 of 9
// bf16x3 cross-terms on v_mfma_f32_32x32x16_bf16 (error ~1.5e-8 vs np fp32 dot,
// same order as the fp32 reorderings that passed rounds 1-4). dist formula,
// zz/cc chains, strict-<-ascending-k argmin all bit-identical to rounds 1-4.
//
// ws layout:
//   float ws_f[0..1024)    cc[k] = |codebook_k|^2
//   uint  ws_u[1024..2048) histogram
//   float ws_f[2048..3072) per-block partial sums
//   byte 12288..471040     codebook bf16x3 splits, 16 chunks x 28672B,
//                          per chunk: [split s][code row cl: 17 x 8B (16 used + pad)]
// If ws_size < 471040 -> fallback fp32 kernel (round-3, known-good).

#define OFF_VQLOSS  4194304
#define OFF_COMMIT  4194305
#define OFF_IDX     4194306
#define OFF_USAGE   4259842
#define OFF_PERP    4259843

#define CBS_BYTE_OFF 12288
#define CHUNK_BYTES  28672          // 3 splits * 64 rows * 17*8B, padded to 7*4*64*16
#define WS_REQUIRED  (CBS_BYTE_OFF + 16 * CHUNK_BYTES)

typedef __attribute__((ext_vector_type(8)))  short short8;   // 8 bf16 = 4 VGPR
typedef __attribute__((ext_vector_type(16))) float f32x16;

__device__ inline unsigned short f2bf(float x) {             // round-to-nearest-even
    unsigned u = __float_as_uint(x);
    return (unsigned short)((u + 0x7FFFu + ((u >> 16) & 1u)) >> 16);
}
__device__ inline float bf2f(unsigned short h) {
    return __uint_as_float(((unsigned)h) << 16);
}
__device__ inline void gload_lds16(const void* g, void* l) { // async 16B global->LDS
    __builtin_amdgcn_global_load_lds((const __attribute__((address_space(1))) void*)g,
                                     (__attribute__((address_space(3))) void*)l, 16, 0, 0);
}

// ---------------- init: cc, hist zero, codebook bf16x3 splits ----------------
__global__ __launch_bounds__(256) void vq_init(const float* __restrict__ cb,
                                               float* __restrict__ ws_f,
                                               unsigned* __restrict__ ws_u,
                                               unsigned long long* __restrict__ cbs8,
                                               int do_cbs) {
    int k = blockIdx.x * 256 + threadIdx.x;    // grid 4x256 -> k in [0,1024)
    ws_u[1024 + k] = 0u;
    const float* row = cb + k * 64;
    float acc = 0.0f;
    #pragma unroll
    for (int d = 0; d < 64; ++d) {
        float v = row[d];
        acc = __fadd_rn(acc, __fmul_rn(v, v));  // ascending chain = rounds 1-4
    }
    ws_f[k] = acc;

    if (!do_cbs) return;
    // splits: c = c1 + c2 + c3 (bf16 each); store packed 4-bf16 per u64,
    // chunk ch = k>>6, row cl = k&63, row stride 17 u64 (16 data + 1 pad).
    const int ch = k >> 6, cl = k & 63;
    unsigned long long* base = cbs8 + (size_t)ch * (CHUNK_BYTES / 8) + (size_t)cl * 17;
    #pragma unroll
    for (int q = 0; q < 8; ++q) {              // q = d-octet
        unsigned long long u[3][2] = {{0,0},{0,0},{0,0}};
        #pragma unroll
        for (int e = 0; e < 8; ++e) {
            float x = row[q * 8 + e];
            unsigned short h1 = f2bf(x);  float r1 = __fsub_rn(x,  bf2f(h1));
            unsigned short h2 = f2bf(r1); float r2 = __fsub_rn(r1, bf2f(h2));
            unsigned short h3 = f2bf(r2);
            const int hw = e >> 2, sh = 16 * (e & 3);
            u[0][hw] |= ((unsigned long long)h1) << sh;
            u[1][hw] |= ((unsigned long long)h2) << sh;
            u[2][hw] |= ((unsigned long long)h3) << sh;
        }
        #pragma unroll
        for (int s = 0; s < 3; ++s) {
            base[(size_t)s * (64 * 17) + q * 2 + 0] = u[s][0];
            base[(size_t)s * (64 * 17) + q * 2 + 1] = u[s][1];
        }
    }
}

// ---------------- main: MFMA distance GEMM + argmin + epilogue ----------------
__global__ __launch_bounds__(256, 1) void vq_main(const float* __restrict__ ze,
                                                  const float* __restrict__ cb,
                                                  const float* __restrict__ ccg,
                                                  const unsigned long long* __restrict__ cbs8,
                                                  unsigned* __restrict__ hist,
                                                  float* __restrict__ partial,
                                                  float* __restrict__ out) {
    const int t   = threadIdx.x;
    const int w   = t >> 6;             // wave 0..3
    const int lane = t & 63;
    const int li  = lane & 31;          // MFMA row/col index
    const int g   = lane >> 5;          // half-wave group
    const int blk = blockIdx.x;         // 256 blocks x 256 vectors

    __shared__ char  chunkbuf[2][CHUNK_BYTES];
    __shared__ float cc_lds[1024];
    __shared__ int   bests[256];
    __shared__ float sred[4];

    // ---- issue stage of chunk 0 (async) ----
    {
        const char* src = (const char*)cbs8;            // chunk 0 at offset 0
        #pragma unroll
        for (int i = 0; i < 7; ++i)
            gload_lds16(src + w * 7168 + i * 1024 + lane * 16,
                        &chunkbuf[0][w * 7168 + i * 1024]);
    }
    // cc -> LDS (overlaps with staging)
    {
        float4 c4 = *reinterpret_cast<const float4*>(ccg + t * 4);
        *reinterpret_cast<float4*>(&cc_lds[t * 4]) = c4;
    }

    // ---- load z, compute zz (ascending chain, bit-identical to R1-4),
    //      build resident bf16x3 B-fragments ----
    float zz[2], bd[2];
    int   bk[2];
    short8 zf[2][3][4];                 // [ntile][split][kc] - all indices unrolled
    #pragma unroll
    for (int nt = 0; nt < 2; ++nt) {
        const int vloc = (w << 6) + (nt << 5) + li;
        const int n    = (blk << 8) + vloc;
        const size_t zb = ((size_t)(n >> 10) << 16) + (size_t)(n & 1023);
        float s = 0.0f;
        #pragma unroll
        for (int d = 0; d < 64; ++d) {
            float x = ze[zb + ((size_t)d << 10)];
            s = __fadd_rn(s, __fmul_rn(x, x));
        }
        zz[nt] = s; bd[nt] = INFINITY; bk[nt] = 0;
        #pragma unroll
        for (int kc = 0; kc < 4; ++kc) {
            unsigned long long u[3][2] = {{0,0},{0,0},{0,0}};
            #pragma unroll
            for (int e = 0; e < 8; ++e) {
                int d = kc * 16 + (g << 3) + e;          // runtime g only in address
                float x = ze[zb + ((size_t)d << 10)];    // L1-hot re-read
                unsigned short h1 = f2bf(x);  float r1 = __fsub_rn(x,  bf2f(h1));
                unsigned short h2 = f2bf(r1); float r2 = __fsub_rn(r1, bf2f(h2));
                unsigned short h3 = f2bf(r2);
                const int hw = e >> 2, sh = 16 * (e & 3);
                u[0][hw] |= ((unsigned long long)h1) << sh;
                u[1][hw] |= ((unsigned long long)h2) << sh;
                u[2][hw] |= ((unsigned long long)h3) << sh;
            }
            #pragma unroll
            for (int s2 = 0; s2 < 3; ++s2) {
                union { unsigned long long uu[2]; short8 v; } cvt;
                cvt.uu[0] = u[s2][0]; cvt.uu[1] = u[s2][1];
                zf[nt][s2][kc] = cvt.v;
            }
        }
    }

    asm volatile("s_waitcnt vmcnt(0)" ::: "memory");
    __syncthreads();

    // ---- 16 chunks of 64 codes, double-buffered ----
    for (int ch = 0; ch < 16; ++ch) {
        const int cur = ch & 1;
        if (ch < 15) {                                   // stage next chunk
            const char* src = (const char*)cbs8 + (size_t)(ch + 1) * CHUNK_BYTES;
            #pragma unroll
            for (int i = 0; i < 7; ++i)
                gload_lds16(src + w * 7168 + i * 1024 + lane * 16,
                            &chunkbuf[cur ^ 1][w * 7168 + i * 1024]);
        }
        const unsigned long long* b8 =
            (const unsigned long long*)&chunkbuf[cur][0];

        #pragma unroll
        for (int kt = 0; kt < 2; ++kt) {                 // 2 k-tiles of 32 codes
            f32x16 aH[2], aL[2];
            #pragma unroll
            for (int nt = 0; nt < 2; ++nt)
                #pragma unroll
                for (int r = 0; r < 16; ++r) { aH[nt][r] = 0.0f; aL[nt][r] = 0.0f; }

            const int cl = kt * 32 + li;                 // code row (A: m = lane&31)
            #pragma unroll
            for (int kc = 0; kc < 4; ++kc) {
                short8 a[3];
                #pragma unroll
                for (int s2 = 0; s2 < 3; ++s2) {         // A-frag: ds_read2_b64, 2-way banks
                    int a8 = s2 * (64 * 17) + cl * 17 + (kc * 2 + g) * 2;
                    union { unsigned long long uu[2]; short8 v; } cvt;
                    cvt.uu[0] = b8[a8]; cvt.uu[1] = b8[a8 + 1];
                    a[s2] = cvt.v;
                }
                #pragma unroll
                for (int nt = 0; nt < 2; ++nt) {
                    // low-order terms, smallest scale first (c_s x z_j), drop c3z3
                    aL[nt] = __builtin_amdgcn_mfma_f32_32x32x16_bf16(a[1], zf[nt][2][kc], aL[nt], 0, 0, 0); // c2 z3
                    aL[nt] = __builtin_amdgcn_mfma_f32_32x32x16_bf16(a[2], zf[nt][1][kc], aL[nt], 0, 0, 0); // c3 z2
                    aL[nt] = __builtin_amdgcn_mfma_f32_32x32x16_bf16(a[1], zf[nt][1][kc], aL[nt], 0, 0, 0); // c2 z2
                    aL[nt] = __builtin_amdgcn_mfma_f32_32x32x16_bf16(a[0], zf[nt][2][kc], aL[nt], 0, 0, 0); // c1 z3
                    aL[nt] = __builtin_amdgcn_mfma_f32_32x32x16_bf16(a[2], zf[nt][0][kc], aL[nt], 0, 0, 0); // c3 z1
                    aL[nt] = __builtin_amdgcn_mfma_f32_32x32x16_bf16(a[0], zf[nt][1][kc], aL[nt], 0, 0, 0); // c1 z2
                    aL[nt] = __builtin_amdgcn_mfma_f32_32x32x16_bf16(a[1], zf[nt][0][kc], aL[nt], 0, 0, 0); // c2 z1
                    aH[nt] = __builtin_amdgcn_mfma_f32_32x32x16_bf16(a[0], zf[nt][0][kc], aH[nt], 0, 0, 0); // c1 z1
                }
            }
            // dist + running argmin. C/D: col=lane&31 (vector), row=(r&3)+8*(r>>2)+4g
            const int k0 = ch * 64 + kt * 32;
            #pragma unroll
            for (int nt = 0; nt < 2; ++nt) {
                #pragma unroll
                for (int j = 0; j < 4; ++j) {
                    float4 c4 = *reinterpret_cast<const float4*>(&cc_lds[k0 + 8 * j + 4 * g]);
                    const float cce[4] = {c4.x, c4.y, c4.z, c4.w};
                    #pragma unroll
                    for (int e = 0; e < 4; ++e) {
                        const int r = 4 * j + e;
                        float dot  = __fadd_rn(aL[nt][r], aH[nt][r]);
                        float dist = __fsub_rn(__fadd_rn(zz[nt], cce[e]),
                                               __fmul_rn(2.0f, dot));
                        const int k = k0 + 8 * j + 4 * g + e;   // ascending within lane
                        if (dist < bd[nt]) { bd[nt] = dist; bk[nt] = k; }
                    }
                }
            }
        }
        asm volatile("s_waitcnt vmcnt(0)" ::: "memory");
        __syncthreads();
    }

    // ---- cross-half argmin merge (packed u64: tie -> lower k) ----
    #pragma unroll
    for (int nt = 0; nt < 2; ++nt) {
        unsigned long long pk =
            (((unsigned long long)__float_as_uint(bd[nt])) << 32) | (unsigned)bk[nt];
        unsigned long long other =
            (unsigned long long)__shfl_xor((long long)pk, 32, 64);
        if (other < pk) pk = other;
        if (g == 0) bests[(w << 6) + (nt << 5) + li] = (int)(pk & 0xFFFFFFFFull);
    }
    __syncthreads();

    // ---- epilogue: thread t <-> block-local vector t ----
    {
        const int n = (blk << 8) + t;
        const size_t zb = ((size_t)(n >> 10) << 16) + (size_t)(n & 1023);
        const int bkv = bests[t];
        out[OFF_IDX + n] = (float)bkv;
        atomicAdd(&hist[bkv], 1u);
        const float4* qrow = reinterpret_cast<const float4*>(cb + ((size_t)bkv << 6));
        float sq = 0.0f;
        #pragma unroll
        for (int j = 0; j < 16; ++j) {
            float4 q4 = qrow[j];
            const float qa[4] = {q4.x, q4.y, q4.z, q4.w};
            #pragma unroll
            for (int e = 0; e < 4; ++e) {
                const int d = 4 * j + e;
                out[zb + ((size_t)d << 10)] = qa[e];          // z_q_st == z_q
                float zx = ze[zb + ((size_t)d << 10)];
                float diff = __fsub_rn(qa[e], zx);
                sq = __fadd_rn(sq, __fmul_rn(diff, diff));
            }
        }
        #pragma unroll
        for (int off = 32; off > 0; off >>= 1) sq += __shfl_down(sq, off, 64);
        if (lane == 0) sred[w] = sq;
    }
    __syncthreads();
    if (t == 0) partial[blk] = (sred[0] + sred[1]) + (sred[2] + sred[3]);
}

// ---------------- fallback fp32 kernel (round-3, known-good) ----------------
__global__ __launch_bounds__(512, 4) void vq_main_fb(const float* __restrict__ ze,
                                                     const float* __restrict__ cb,
                                                     const float* __restrict__ cc,
                                                     unsigned* __restrict__ hist,
                                                     float* __restrict__ partial,
                                                     float* __restrict__ out) {
    const int lane = threadIdx.x & 63;
    const int w = __builtin_amdgcn_readfirstlane(threadIdx.x >> 6);
    const int n  = blockIdx.x * 64 + lane;
    const int b  = n >> 10;
    const int hw = n & 1023;
    const size_t zbase = ((size_t)b << 16) + (size_t)hw;
    float z[64];
    #pragma unroll
    for (int d = 0; d < 64; ++d) z[d] = ze[zbase + ((size_t)d << 10)];
    float zz = 0.0f;
    #pragma unroll
    for (int d = 0; d < 64; ++d) zz = __fadd_rn(zz, __fmul_rn(z[d], z[d]));
    float best = INFINITY; int bestk = 0;
    const int k0 = w << 7;
    for (int kk = 0; kk < 128; ++kk) {
        const int k = k0 + kk;
        const float4* crow = reinterpret_cast<const float4*>(cb + (k << 6));
        float p[4] = {0.0f, 0.0f, 0.0f, 0.0f};
        #pragma unroll
        for (int j = 0; j < 16; ++j) {
            float4 c4 = crow[j];
            p[j & 3] = fmaf(z[4*j + 0], c4.x, p[j & 3]);
            p[j & 3] = fmaf(z[4*j + 1], c4.y, p[j & 3]);
            p[j & 3] = fmaf(z[4*j + 2], c4.z, p[j & 3]);
            p[j & 3] = fmaf(z[4*j + 3], c4.w, p[j & 3]);
        }
        float dot  = __fadd_rn(__fadd_rn(p[0], p[1]), __fadd_rn(p[2], p[3]));
        float dist = __fsub_rn(__fadd_rn(zz, cc[k]), __fmul_rn(2.0f, dot));
        if (dist < best) { best = dist; bestk = k; }
    }
    __shared__ float s_best[7][64];
    __shared__ int   s_bk[7][64];
    if (w > 0) { s_best[w - 1][lane] = best; s_bk[w - 1][lane] = bestk; }
    __syncthreads();
    if (w == 0) {
        #pragma unroll
        for (int i = 0; i < 7; ++i) {
            float b2 = s_best[i][lane]; int k2 = s_bk[i][lane];
            if (b2 < best) { best = b2; bestk = k2; }
        }
        const float4* qrow = reinterpret_cast<const float4*>(cb + (bestk << 6));
        float sq = 0.0f;
        #pragma unroll
        for (int j = 0; j < 16; ++j) {
            float4 q4 = qrow[j];
            const float q[4] = {q4.x, q4.y, q4.z, q4.w};
            #pragma unroll
            for (int e = 0; e < 4; ++e) {
                int d = 4*j + e;
                out[zbase + ((size_t)d << 10)] = q[e];
                float diff = __fsub_rn(q[e], z[d]);
                sq = __fadd_rn(sq, __fmul_rn(diff, diff));
            }
        }
        out[OFF_IDX + n] = (float)bestk;
        atomicAdd(&hist[bestk], 1u);
        #pragma unroll
        for (int off = 32; off > 0; off >>= 1) sq += __shfl_down(sq, off, 64);
        if (lane == 0) partial[blockIdx.x] = sq;
    }
}

// ---------------- finalize ----------------
__global__ __launch_bounds__(256) void vq_fin(const float* __restrict__ partial,
                                              const unsigned* __restrict__ hist,
                                              float* __restrict__ out, int nb) {
    const int t = threadIdx.x;
    const int wid = t >> 6, lane = t & 63;
    __shared__ float s_loss[4], s_ent[4], s_nz[4];
    float v = 0.0f, ent = 0.0f, nz = 0.0f;
    for (int i = t; i < nb; i += 256) v += partial[i];
    #pragma unroll
    for (int i = 0; i < 4; ++i) {
        unsigned c = hist[t + 256 * i];
        float p = (float)c * (1.0f / 65536.0f);
        ent += p * logf(p + 1e-10f);
        if (c > 0u) nz += 1.0f;
    }
    #pragma unroll
    for (int off = 32; off > 0; off >>= 1) {
        v   += __shfl_down(v,   off, 64);
        ent += __shfl_down(ent, off, 64);
        nz  += __shfl_down(nz,  off, 64);
    }
    if (lane == 0) { s_loss[wid] = v; s_ent[wid] = ent; s_nz[wid] = nz; }
    __syncthreads();
    if (t == 0) {
        float S  = (s_loss[0] + s_loss[1]) + (s_loss[2] + s_loss[3]);
        float vq = S * (1.0f / 4194304.0f);
        out[OFF_VQLOSS] = vq;
        out[OFF_COMMIT] = 0.25f * vq;
        float E  = (s_ent[0] + s_ent[1]) + (s_ent[2] + s_ent[3]);
        float NZ = (s_nz[0] + s_nz[1]) + (s_nz[2] + s_nz[3]);
        out[OFF_USAGE] = NZ * (1.0f / 1024.0f);
        out[OFF_PERP]  = expf(-E);
    }
}

extern "C" void kernel_launch(void* const* d_in, const int* in_sizes, int n_in,
                              void* d_out, int out_size, void* d_ws, size_t ws_size,
                              hipStream_t stream) {
    const float* ze = (const float*)d_in[0];
    const float* cb = (const float*)d_in[1];
    float*    out  = (float*)d_out;
    float*    ws_f = (float*)d_ws;
    unsigned* ws_u = (unsigned*)d_ws;
    unsigned long long* cbs8 =
        (unsigned long long*)((char*)d_ws + CBS_BYTE_OFF);

    const int use_mfma = (ws_size >= (size_t)WS_REQUIRED);

    vq_init<<<dim3(4), dim3(256), 0, stream>>>(cb, ws_f, ws_u, cbs8, use_mfma);
    if (use_mfma) {
        vq_main<<<dim3(256), dim3(256), 0, stream>>>(ze, cb, ws_f, cbs8,
                                                     ws_u + 1024, ws_f + 2048, out);
        vq_fin<<<dim3(1), dim3(256), 0, stream>>>(ws_f + 2048, ws_u + 1024, out, 256);
    } else {
        vq_main_fb<<<dim3(1024), dim3(512), 0, stream>>>(ze, cb, ws_f, ws_u + 1024,
                                                         ws_f + 2048, out);
        vq_fin<<<dim3(1), dim3(256), 0, stream>>>(ws_f + 2048, ws_u + 1024, out, 1024);
    }
}

// Round 6
// 83.621 us; speedup vs baseline: 2.0600x; 1.1740x over previous
//
#include <hip/hip_runtime.h>
#include <math.h>

// VQ-VAE quantizer, MI355X. N=65536 vectors (B64*H32*W32), D=64, K=1024.
// Round-6: bf16x3 MFMA GEMM, occupancy-fixed.
//  R5 evidence: MFMA work 27.5us @ MfmaUtil 30% -> pipe idle; grid 256 = exactly
//  1 block/CU (Occ 10.2%), per-chunk barrier drains with no co-resident waves.
//  Fixes: (a) 128 vec/block -> grid 512 = 2 blocks/CU (LDS 62KB < 80KB), 8 waves/CU;
//         (b) 8 -> 6 bf16x3 cross-terms in 3 independent accumulator chains
//             (dropped c3z2+c2z3 ~ 2e-10 abs error, 100x below the fp32-reorder
//              deltas that passed rounds 1-5; dist grid ulp(64)=7.6e-6).
//  dist formula fl(fl(zz+cc) - fl(2*dot)), zz/cc ascending chains, tie->lower-k:
//  all bit-identical to rounds 1-5.
//
// ws layout:
//   float ws_f[0..1024)    cc[k] = |codebook_k|^2
//   uint  ws_u[1024..2048) histogram
//   float ws_f[2048..2560) per-block partial sums (512 blocks)
//   byte 12288..471040     codebook bf16x3 splits, 16 chunks x 28672B
// If ws_size < 471040 -> fallback fp32 kernel (round-3, known-good).

#define OFF_VQLOSS  4194304
#define OFF_COMMIT  4194305
#define OFF_IDX     4194306
#define OFF_USAGE   4259842
#define OFF_PERP    4259843

#define CBS_BYTE_OFF 12288
#define CHUNK_BYTES  28672          // 3 splits * 64 rows * 17*8B (16 used + 1 pad)
#define WS_REQUIRED  (CBS_BYTE_OFF + 16 * CHUNK_BYTES)

typedef __attribute__((ext_vector_type(8)))  short short8;   // 8 bf16 = 4 VGPR
typedef __attribute__((ext_vector_type(16))) float f32x16;

__device__ inline unsigned short f2bf(float x) {             // round-to-nearest-even
    unsigned u = __float_as_uint(x);
    return (unsigned short)((u + 0x7FFFu + ((u >> 16) & 1u)) >> 16);
}
__device__ inline float bf2f(unsigned short h) {
    return __uint_as_float(((unsigned)h) << 16);
}
__device__ inline void gload_lds16(const void* g, void* l) { // async 16B global->LDS
    __builtin_amdgcn_global_load_lds((const __attribute__((address_space(1))) void*)g,
                                     (__attribute__((address_space(3))) void*)l, 16, 0, 0);
}

// ---------------- init: cc, hist zero, codebook bf16x3 splits ----------------
__global__ __launch_bounds__(256) void vq_init(const float* __restrict__ cb,
                                               float* __restrict__ ws_f,
                                               unsigned* __restrict__ ws_u,
                                               unsigned long long* __restrict__ cbs8,
                                               int do_cbs) {
    int k = blockIdx.x * 256 + threadIdx.x;    // grid 4x256 -> k in [0,1024)
    ws_u[1024 + k] = 0u;
    const float* row = cb + k * 64;
    float acc = 0.0f;
    #pragma unroll
    for (int d = 0; d < 64; ++d) {
        float v = row[d];
        acc = __fadd_rn(acc, __fmul_rn(v, v));  // ascending chain = rounds 1-5
    }
    ws_f[k] = acc;

    if (!do_cbs) return;
    const int ch = k >> 6, cl = k & 63;
    unsigned long long* base = cbs8 + (size_t)ch * (CHUNK_BYTES / 8) + (size_t)cl * 17;
    #pragma unroll
    for (int q = 0; q < 8; ++q) {              // q = d-octet
        unsigned long long u[3][2] = {{0,0},{0,0},{0,0}};
        #pragma unroll
        for (int e = 0; e < 8; ++e) {
            float x = row[q * 8 + e];
            unsigned short h1 = f2bf(x);  float r1 = __fsub_rn(x,  bf2f(h1));
            unsigned short h2 = f2bf(r1); float r2 = __fsub_rn(r1, bf2f(h2));
            unsigned short h3 = f2bf(r2);
            const int hw = e >> 2, sh = 16 * (e & 3);
            u[0][hw] |= ((unsigned long long)h1) << sh;
            u[1][hw] |= ((unsigned long long)h2) << sh;
            u[2][hw] |= ((unsigned long long)h3) << sh;
        }
        #pragma unroll
        for (int s = 0; s < 3; ++s) {
            base[(size_t)s * (64 * 17) + q * 2 + 0] = u[s][0];
            base[(size_t)s * (64 * 17) + q * 2 + 1] = u[s][1];
        }
    }
}

// ---------------- main: MFMA distance GEMM + argmin + epilogue ----------------
// 512 blocks x 128 vectors; 4 waves/block, wave w owns vectors w*32..w*32+31.
__global__ __launch_bounds__(256, 2) void vq_main(const float* __restrict__ ze,
                                                  const float* __restrict__ cb,
                                                  const float* __restrict__ ccg,
                                                  const unsigned long long* __restrict__ cbs8,
                                                  unsigned* __restrict__ hist,
                                                  float* __restrict__ partial,
                                                  float* __restrict__ out) {
    const int t    = threadIdx.x;
    const int w    = t >> 6;            // wave 0..3
    const int lane = t & 63;
    const int li   = lane & 31;         // MFMA row/col index
    const int g    = lane >> 5;         // half-wave group (k-octet select)
    const int blk  = blockIdx.x;        // 512 blocks x 128 vectors

    __shared__ char  chunkbuf[2][CHUNK_BYTES];
    __shared__ float cc_lds[1024];
    __shared__ int   bests[128];
    __shared__ float sred[2];

    // ---- issue stage of chunk 0 (async) ----
    {
        const char* src = (const char*)cbs8;            // chunk 0 at offset 0
        #pragma unroll
        for (int i = 0; i < 7; ++i)
            gload_lds16(src + w * 7168 + i * 1024 + lane * 16,
                        &chunkbuf[0][w * 7168 + i * 1024]);
    }
    // cc -> LDS (overlaps with staging)
    {
        float4 c4 = *reinterpret_cast<const float4*>(ccg + t * 4);
        *reinterpret_cast<float4*>(&cc_lds[t * 4]) = c4;
    }

    // ---- load z, compute zz (ascending chain, bit-identical to R1-5),
    //      build resident bf16x3 B-fragments (this wave's 32 vectors) ----
    const int vloc = (w << 5) + li;
    const int n    = (blk << 7) + vloc;
    const size_t zb = ((size_t)(n >> 10) << 16) + (size_t)(n & 1023);
    float zz, bd;
    int   bk;
    short8 zf[3][4];                    // [split][kc]
    {
        float s = 0.0f;
        #pragma unroll
        for (int d = 0; d < 64; ++d) {
            float x = ze[zb + ((size_t)d << 10)];
            s = __fadd_rn(s, __fmul_rn(x, x));
        }
        zz = s; bd = INFINITY; bk = 0;
        #pragma unroll
        for (int kc = 0; kc < 4; ++kc) {
            unsigned long long u[3][2] = {{0,0},{0,0},{0,0}};
            #pragma unroll
            for (int e = 0; e < 8; ++e) {
                int d = kc * 16 + (g << 3) + e;
                float x = ze[zb + ((size_t)d << 10)];    // L1-hot re-read
                unsigned short h1 = f2bf(x);  float r1 = __fsub_rn(x,  bf2f(h1));
                unsigned short h2 = f2bf(r1); float r2 = __fsub_rn(r1, bf2f(h2));
                unsigned short h3 = f2bf(r2);
                const int hw = e >> 2, sh = 16 * (e & 3);
                u[0][hw] |= ((unsigned long long)h1) << sh;
                u[1][hw] |= ((unsigned long long)h2) << sh;
                u[2][hw] |= ((unsigned long long)h3) << sh;
            }
            #pragma unroll
            for (int s2 = 0; s2 < 3; ++s2) {
                union { unsigned long long uu[2]; short8 v; } cvt;
                cvt.uu[0] = u[s2][0]; cvt.uu[1] = u[s2][1];
                zf[s2][kc] = cvt.v;
            }
        }
    }

    asm volatile("s_waitcnt vmcnt(0)" ::: "memory");
    __syncthreads();

    // ---- 16 chunks of 64 codes, double-buffered ----
    for (int ch = 0; ch < 16; ++ch) {
        const int cur = ch & 1;
        if (ch < 15) {                                   // stage next chunk
            const char* src = (const char*)cbs8 + (size_t)(ch + 1) * CHUNK_BYTES;
            #pragma unroll
            for (int i = 0; i < 7; ++i)
                gload_lds16(src + w * 7168 + i * 1024 + lane * 16,
                            &chunkbuf[cur ^ 1][w * 7168 + i * 1024]);
        }
        const unsigned long long* b8 =
            (const unsigned long long*)&chunkbuf[cur][0];

        #pragma unroll
        for (int kt = 0; kt < 2; ++kt) {                 // 2 k-tiles of 32 codes
            f32x16 aH, aM, aL;
            #pragma unroll
            for (int r = 0; r < 16; ++r) { aH[r] = 0.0f; aM[r] = 0.0f; aL[r] = 0.0f; }

            const int cl = kt * 32 + li;                 // code row (A: m = lane&31)
            #pragma unroll
            for (int kc = 0; kc < 4; ++kc) {
                short8 a[3];
                #pragma unroll
                for (int s2 = 0; s2 < 3; ++s2) {         // adjacent u64 pair: ds_read2_b64
                    int a8 = s2 * (64 * 17) + cl * 17 + (kc * 2 + g) * 2;
                    union { unsigned long long uu[2]; short8 v; } cvt;
                    cvt.uu[0] = b8[a8]; cvt.uu[1] = b8[a8 + 1];
                    a[s2] = cvt.v;
                }
                // 6 terms, 3 independent chains (drop c3z2, c2z3, c3z3)
                aL = __builtin_amdgcn_mfma_f32_32x32x16_bf16(a[1], zf[1][kc], aL, 0, 0, 0); // c2 z2
                aL = __builtin_amdgcn_mfma_f32_32x32x16_bf16(a[2], zf[0][kc], aL, 0, 0, 0); // c3 z1
                aL = __builtin_amdgcn_mfma_f32_32x32x16_bf16(a[0], zf[2][kc], aL, 0, 0, 0); // c1 z3
                aM = __builtin_amdgcn_mfma_f32_32x32x16_bf16(a[1], zf[0][kc], aM, 0, 0, 0); // c2 z1
                aM = __builtin_amdgcn_mfma_f32_32x32x16_bf16(a[0], zf[1][kc], aM, 0, 0, 0); // c1 z2
                aH = __builtin_amdgcn_mfma_f32_32x32x16_bf16(a[0], zf[0][kc], aH, 0, 0, 0); // c1 z1
            }
            // dist + running argmin. C/D: col=lane&31 (vector), row=(r&3)+8*(r>>2)+4g
            const int k0 = ch * 64 + kt * 32;
            #pragma unroll
            for (int j = 0; j < 4; ++j) {
                float4 c4 = *reinterpret_cast<const float4*>(&cc_lds[k0 + 8 * j + 4 * g]);
                const float cce[4] = {c4.x, c4.y, c4.z, c4.w};
                #pragma unroll
                for (int e = 0; e < 4; ++e) {
                    const int r = 4 * j + e;
                    float dot  = __fadd_rn(__fadd_rn(aL[r], aM[r]), aH[r]);
                    float dist = __fsub_rn(__fadd_rn(zz, cce[e]),
                                           __fmul_rn(2.0f, dot));
                    const int k = k0 + 8 * j + 4 * g + e;   // ascending within lane
                    if (dist < bd) { bd = dist; bk = k; }
                }
            }
        }
        asm volatile("s_waitcnt vmcnt(0)" ::: "memory");
        __syncthreads();
    }

    // ---- cross-half argmin merge (packed u64: tie -> lower k) ----
    {
        unsigned long long pk =
            (((unsigned long long)__float_as_uint(bd)) << 32) | (unsigned)bk;
        unsigned long long other =
            (unsigned long long)__shfl_xor((long long)pk, 32, 64);
        if (other < pk) pk = other;
        if (g == 0) bests[vloc] = (int)(pk & 0xFFFFFFFFull);
    }
    __syncthreads();

    // ---- epilogue: thread t < 128 <-> block-local vector t ----
    if (t < 128) {
        const int nn = (blk << 7) + t;
        const size_t zb2 = ((size_t)(nn >> 10) << 16) + (size_t)(nn & 1023);
        const int bkv = bests[t];
        out[OFF_IDX + nn] = (float)bkv;
        atomicAdd(&hist[bkv], 1u);
        const float4* qrow = reinterpret_cast<const float4*>(cb + ((size_t)bkv << 6));
        float sq = 0.0f;
        #pragma unroll
        for (int j = 0; j < 16; ++j) {
            float4 q4 = qrow[j];
            const float qa[4] = {q4.x, q4.y, q4.z, q4.w};
            #pragma unroll
            for (int e = 0; e < 4; ++e) {
                const int d = 4 * j + e;
                out[zb2 + ((size_t)d << 10)] = qa[e];        // z_q_st == z_q
                float zx = ze[zb2 + ((size_t)d << 10)];
                float diff = __fsub_rn(qa[e], zx);
                sq = __fadd_rn(sq, __fmul_rn(diff, diff));
            }
        }
        #pragma unroll
        for (int off = 32; off > 0; off >>= 1) sq += __shfl_down(sq, off, 64);
        if (lane == 0) sred[t >> 6] = sq;
    }
    __syncthreads();
    if (t == 0) partial[blk] = sred[0] + sred[1];
}

// ---------------- fallback fp32 kernel (round-3, known-good) ----------------
__global__ __launch_bounds__(512, 4) void vq_main_fb(const float* __restrict__ ze,
                                                     const float* __restrict__ cb,
                                                     const float* __restrict__ cc,
                                                     unsigned* __restrict__ hist,
                                                     float* __restrict__ partial,
                                                     float* __restrict__ out) {
    const int lane = threadIdx.x & 63;
    const int w = __builtin_amdgcn_readfirstlane(threadIdx.x >> 6);
    const int n  = blockIdx.x * 64 + lane;
    const int b  = n >> 10;
    const int hw = n & 1023;
    const size_t zbase = ((size_t)b << 16) + (size_t)hw;
    float z[64];
    #pragma unroll
    for (int d = 0; d < 64; ++d) z[d] = ze[zbase + ((size_t)d << 10)];
    float zz = 0.0f;
    #pragma unroll
    for (int d = 0; d < 64; ++d) zz = __fadd_rn(zz, __fmul_rn(z[d], z[d]));
    float best = INFINITY; int bestk = 0;
    const int k0 = w << 7;
    for (int kk = 0; kk < 128; ++kk) {
        const int k = k0 + kk;
        const float4* crow = reinterpret_cast<const float4*>(cb + (k << 6));
        float p[4] = {0.0f, 0.0f, 0.0f, 0.0f};
        #pragma unroll
        for (int j = 0; j < 16; ++j) {
            float4 c4 = crow[j];
            p[j & 3] = fmaf(z[4*j + 0], c4.x, p[j & 3]);
            p[j & 3] = fmaf(z[4*j + 1], c4.y, p[j & 3]);
            p[j & 3] = fmaf(z[4*j + 2], c4.z, p[j & 3]);
            p[j & 3] = fmaf(z[4*j + 3], c4.w, p[j & 3]);
        }
        float dot  = __fadd_rn(__fadd_rn(p[0], p[1]), __fadd_rn(p[2], p[3]));
        float dist = __fsub_rn(__fadd_rn(zz, cc[k]), __fmul_rn(2.0f, dot));
        if (dist < best) { best = dist; bestk = k; }
    }
    __shared__ float s_best[7][64];
    __shared__ int   s_bk[7][64];
    if (w > 0) { s_best[w - 1][lane] = best; s_bk[w - 1][lane] = bestk; }
    __syncthreads();
    if (w == 0) {
        #pragma unroll
        for (int i = 0; i < 7; ++i) {
            float b2 = s_best[i][lane]; int k2 = s_bk[i][lane];
            if (b2 < best) { best = b2; bestk = k2; }
        }
        const float4* qrow = reinterpret_cast<const float4*>(cb + (bestk << 6));
        float sq = 0.0f;
        #pragma unroll
        for (int j = 0; j < 16; ++j) {
            float4 q4 = qrow[j];
            const float q[4] = {q4.x, q4.y, q4.z, q4.w};
            #pragma unroll
            for (int e = 0; e < 4; ++e) {
                int d = 4*j + e;
                out[zbase + ((size_t)d << 10)] = q[e];
                float diff = __fsub_rn(q[e], z[d]);
                sq = __fadd_rn(sq, __fmul_rn(diff, diff));
            }
        }
        out[OFF_IDX + n] = (float)bestk;
        atomicAdd(&hist[bestk], 1u);
        #pragma unroll
        for (int off = 32; off > 0; off >>= 1) sq += __shfl_down(sq, off, 64);
        if (lane == 0) partial[blockIdx.x] = sq;
    }
}

// ---------------- finalize ----------------
__global__ __launch_bounds__(256) void vq_fin(const float* __restrict__ partial,
                                              const unsigned* __restrict__ hist,
                                              float* __restrict__ out, int nb) {
    const int t = threadIdx.x;
    const int wid = t >> 6, lane = t & 63;
    __shared__ float s_loss[4], s_ent[4], s_nz[4];
    float v = 0.0f, ent = 0.0f, nz = 0.0f;
    for (int i = t; i < nb; i += 256) v += partial[i];
    #pragma unroll
    for (int i = 0; i < 4; ++i) {
        unsigned c = hist[t + 256 * i];
        float p = (float)c * (1.0f / 65536.0f);
        ent += p * logf(p + 1e-10f);
        if (c > 0u) nz += 1.0f;
    }
    #pragma unroll
    for (int off = 32; off > 0; off >>= 1) {
        v   += __shfl_down(v,   off, 64);
        ent += __shfl_down(ent, off, 64);
        nz  += __shfl_down(nz,  off, 64);
    }
    if (lane == 0) { s_loss[wid] = v; s_ent[wid] = ent; s_nz[wid] = nz; }
    __syncthreads();
    if (t == 0) {
        float S  = (s_loss[0] + s_loss[1]) + (s_loss[2] + s_loss[3]);
        float vq = S * (1.0f / 4194304.0f);
        out[OFF_VQLOSS] = vq;
        out[OFF_COMMIT] = 0.25f * vq;
        float E  = (s_ent[0] + s_ent[1]) + (s_ent[2] + s_ent[3]);
        float NZ = (s_nz[0] + s_nz[1]) + (s_nz[2] + s_nz[3]);
        out[OFF_USAGE] = NZ * (1.0f / 1024.0f);
        out[OFF_PERP]  = expf(-E);
    }
}

extern "C" void kernel_launch(void* const* d_in, const int* in_sizes, int n_in,
                              void* d_out, int out_size, void* d_ws, size_t ws_size,
                              hipStream_t stream) {
    const float* ze = (const float*)d_in[0];
    const float* cb = (const float*)d_in[1];
    float*    out  = (float*)d_out;
    float*    ws_f = (float*)d_ws;
    unsigned* ws_u = (unsigned*)d_ws;
    unsigned long long* cbs8 =
        (unsigned long long*)((char*)d_ws + CBS_BYTE_OFF);

    const int use_mfma = (ws_size >= (size_t)WS_REQUIRED);

    vq_init<<<dim3(4), dim3(256), 0, stream>>>(cb, ws_f, ws_u, cbs8, use_mfma);
    if (use_mfma) {
        vq_main<<<dim3(512), dim3(256), 0, stream>>>(ze, cb, ws_f, cbs8,
                                                     ws_u + 1024, ws_f + 2048, out);
        vq_fin<<<dim3(1), dim3(256), 0, stream>>>(ws_f + 2048, ws_u + 1024, out, 512);
    } else {
        vq_main_fb<<<dim3(1024), dim3(512), 0, stream>>>(ze, cb, ws_f, ws_u + 1024,
                                                         ws_f + 2048, out);
        vq_fin<<<dim3(1), dim3(256), 0, stream>>>(ws_f + 2048, ws_u + 1024, out, 1024);
    }
}

// Round 7
// 79.828 us; speedup vs baseline: 2.1579x; 1.0475x over previous
//
#include <hip/hip_runtime.h>
#include <math.h>

// VQ-VAE quantizer, MI355X. N=65536 vectors (B64*H32*W32), D=64, K=1024.
// Round-7: bf16x3 MFMA GEMM + K-split x2 for full wave residency.
//  R6 evidence: MfmaUtil pinned ~31% with model-consistent MFMA time (21us of
//  69); only 2 waves/SIMD resident because wave granularity = 32 vectors =>
//  2048 waves total. Fix: each wave scans HALF the codebook (K-split 2) =>
//  4096 waves = 16/CU = 4/SIMD, grid 512 x 512thr fully resident.
//  Block = 8 waves: group grp=w>>2 handles codes [512*grp, 512*grp+512) in 16
//  chunks of 32 codes; 128 vectors shared; argmin merged via LDS u64 atomicMin
//  (packed (dist,k), order-independent, ties -> lower k; R4-proven).
//  All numerics bit-identical to rounds 5/6 (6-term bf16x3, dist formula,
//  ascending chains).
//
// ws layout:
//   float ws_f[0..1024)    cc[k] = |codebook_k|^2
//   uint  ws_u[1024..2048) histogram
//   float ws_f[2048..2560) per-block partial sums (512 blocks)
//   byte 12288..438272     codebook bf16x3 splits, 32 chunks x 13312B
//                          per chunk: [split s: 544 u64][row cl: 17 u64 (16+pad)]
// If ws_size < 438272 -> fallback fp32 kernel (round-3, known-good).

#define OFF_VQLOSS  4194304
#define OFF_COMMIT  4194305
#define OFF_IDX     4194306
#define OFF_USAGE   4259842
#define OFF_PERP    4259843

#define CBS_BYTE_OFF 12288
#define CHUNK_BYTES  13312          // 3 splits * 32 rows * 17*8B = 13056, pad to 13*1024
#define N_CHUNKS     32
#define WS_REQUIRED  (CBS_BYTE_OFF + N_CHUNKS * CHUNK_BYTES)

typedef __attribute__((ext_vector_type(8)))  short short8;   // 8 bf16 = 4 VGPR
typedef __attribute__((ext_vector_type(16))) float f32x16;

__device__ inline unsigned short f2bf(float x) {             // round-to-nearest-even
    unsigned u = __float_as_uint(x);
    return (unsigned short)((u + 0x7FFFu + ((u >> 16) & 1u)) >> 16);
}
__device__ inline float bf2f(unsigned short h) {
    return __uint_as_float(((unsigned)h) << 16);
}
__device__ inline void gload_lds16(const void* g, void* l) { // async 16B global->LDS
    __builtin_amdgcn_global_load_lds((const __attribute__((address_space(1))) void*)g,
                                     (__attribute__((address_space(3))) void*)l, 16, 0, 0);
}

// ---------------- init: cc, hist zero, codebook bf16x3 splits ----------------
__global__ __launch_bounds__(256) void vq_init(const float* __restrict__ cb,
                                               float* __restrict__ ws_f,
                                               unsigned* __restrict__ ws_u,
                                               unsigned long long* __restrict__ cbs8,
                                               int do_cbs) {
    int k = blockIdx.x * 256 + threadIdx.x;    // grid 4x256 -> k in [0,1024)
    ws_u[1024 + k] = 0u;
    const float* row = cb + k * 64;
    float acc = 0.0f;
    #pragma unroll
    for (int d = 0; d < 64; ++d) {
        float v = row[d];
        acc = __fadd_rn(acc, __fmul_rn(v, v));  // ascending chain = rounds 1-6
    }
    ws_f[k] = acc;

    if (!do_cbs) return;
    // chunk ch = k>>5 (32 codes/chunk), row cl = k&31; row = 17 u64 (16 + pad)
    const int ch = k >> 5, cl = k & 31;
    unsigned long long* base = cbs8 + (size_t)ch * (CHUNK_BYTES / 8) + (size_t)cl * 17;
    #pragma unroll
    for (int q = 0; q < 8; ++q) {              // q = d-octet
        unsigned long long u[3][2] = {{0,0},{0,0},{0,0}};
        #pragma unroll
        for (int e = 0; e < 8; ++e) {
            float x = row[q * 8 + e];
            unsigned short h1 = f2bf(x);  float r1 = __fsub_rn(x,  bf2f(h1));
            unsigned short h2 = f2bf(r1); float r2 = __fsub_rn(r1, bf2f(h2));
            unsigned short h3 = f2bf(r2);
            const int hw = e >> 2, sh = 16 * (e & 3);
            u[0][hw] |= ((unsigned long long)h1) << sh;
            u[1][hw] |= ((unsigned long long)h2) << sh;
            u[2][hw] |= ((unsigned long long)h3) << sh;
        }
        #pragma unroll
        for (int s = 0; s < 3; ++s) {
            base[(size_t)s * 544 + q * 2 + 0] = u[s][0];   // 544 = 32*17 u64/split
            base[(size_t)s * 544 + q * 2 + 1] = u[s][1];
        }
    }
}

// ---------------- main: MFMA distance GEMM + argmin + epilogue ----------------
// 512 blocks x 128 vectors; 8 waves: group grp=w>>2 scans K-half grp,
// wave-in-group wg=w&3 owns vectors wg*32..wg*32+31.
__global__ __launch_bounds__(512, 4) void vq_main(const float* __restrict__ ze,
                                                  const float* __restrict__ cb,
                                                  const float* __restrict__ ccg,
                                                  const unsigned long long* __restrict__ cbs8,
                                                  unsigned* __restrict__ hist,
                                                  float* __restrict__ partial,
                                                  float* __restrict__ out) {
    const int t    = threadIdx.x;
    const int w    = t >> 6;            // wave 0..7
    const int lane = t & 63;
    const int li   = lane & 31;         // MFMA row/col index
    const int g    = lane >> 5;         // half-wave group (k-octet select)
    const int grp  = w >> 2;            // K-half 0/1
    const int wg   = w & 3;             // wave within group
    const int blk  = blockIdx.x;        // 512 blocks x 128 vectors

    __shared__ char  chunkbuf[2][2][CHUNK_BYTES];   // [grp][dbuf]
    __shared__ float cc_lds[1024];
    __shared__ unsigned long long best[128];
    __shared__ float sred[2];

    // ---- issue stage of this group's chunk 0 (async; 13 KB rounds, ragged) ----
    {
        const char* src = (const char*)cbs8 + (size_t)(grp * 16) * CHUNK_BYTES;
        char* dst = &chunkbuf[grp][0][0];
        for (int r = wg; r < 13; r += 4)
            gload_lds16(src + r * 1024 + lane * 16, dst + r * 1024);
    }
    if (t < 256) {                       // cc -> LDS (overlaps staging)
        float4 c4 = *reinterpret_cast<const float4*>(ccg + t * 4);
        *reinterpret_cast<float4*>(&cc_lds[t * 4]) = c4;
    }
    if (t < 128) best[t] = ~0ull;

    // ---- load z, compute zz (ascending chain, bit-identical to R1-6),
    //      build resident bf16x3 B-fragments (this wave's 32 vectors) ----
    const int vloc = (wg << 5) + li;
    const int n    = (blk << 7) + vloc;
    const size_t zb = ((size_t)(n >> 10) << 16) + (size_t)(n & 1023);
    float zz, bd;
    int   bk;
    short8 zf[3][4];                    // [split][kc]
    {
        float s = 0.0f;
        #pragma unroll
        for (int d = 0; d < 64; ++d) {
            float x = ze[zb + ((size_t)d << 10)];
            s = __fadd_rn(s, __fmul_rn(x, x));
        }
        zz = s; bd = INFINITY; bk = 0;
        #pragma unroll
        for (int kc = 0; kc < 4; ++kc) {
            unsigned long long u[3][2] = {{0,0},{0,0},{0,0}};
            #pragma unroll
            for (int e = 0; e < 8; ++e) {
                int d = kc * 16 + (g << 3) + e;
                float x = ze[zb + ((size_t)d << 10)];    // L1-hot re-read
                unsigned short h1 = f2bf(x);  float r1 = __fsub_rn(x,  bf2f(h1));
                unsigned short h2 = f2bf(r1); float r2 = __fsub_rn(r1, bf2f(h2));
                unsigned short h3 = f2bf(r2);
                const int hw = e >> 2, sh = 16 * (e & 3);
                u[0][hw] |= ((unsigned long long)h1) << sh;
                u[1][hw] |= ((unsigned long long)h2) << sh;
                u[2][hw] |= ((unsigned long long)h3) << sh;
            }
            #pragma unroll
            for (int s2 = 0; s2 < 3; ++s2) {
                union { unsigned long long uu[2]; short8 v; } cvt;
                cvt.uu[0] = u[s2][0]; cvt.uu[1] = u[s2][1];
                zf[s2][kc] = cvt.v;
            }
        }
    }

    asm volatile("s_waitcnt vmcnt(0)" ::: "memory");
    __syncthreads();

    // ---- 16 chunks of 32 codes per group, double-buffered ----
    for (int ci = 0; ci < 16; ++ci) {
        const int cur = ci & 1;
        if (ci < 15) {                                   // stage next chunk
            const char* src = (const char*)cbs8
                            + (size_t)(grp * 16 + ci + 1) * CHUNK_BYTES;
            char* dst = &chunkbuf[grp][cur ^ 1][0];
            for (int r = wg; r < 13; r += 4)
                gload_lds16(src + r * 1024 + lane * 16, dst + r * 1024);
        }
        const unsigned long long* b8 =
            (const unsigned long long*)&chunkbuf[grp][cur][0];

        f32x16 aH, aM, aL;
        #pragma unroll
        for (int r = 0; r < 16; ++r) { aH[r] = 0.0f; aM[r] = 0.0f; aL[r] = 0.0f; }

        const int cl = li;                               // code row (A: m = lane&31)
        #pragma unroll
        for (int kc = 0; kc < 4; ++kc) {
            short8 a[3];
            #pragma unroll
            for (int s2 = 0; s2 < 3; ++s2) {             // adjacent u64 pair
                int a8 = s2 * 544 + cl * 17 + (kc * 2 + g) * 2;
                union { unsigned long long uu[2]; short8 v; } cvt;
                cvt.uu[0] = b8[a8]; cvt.uu[1] = b8[a8 + 1];
                a[s2] = cvt.v;
            }
            // 6 terms, 3 independent chains (drop c3z2, c2z3, c3z3)
            aL = __builtin_amdgcn_mfma_f32_32x32x16_bf16(a[1], zf[1][kc], aL, 0, 0, 0); // c2 z2
            aL = __builtin_amdgcn_mfma_f32_32x32x16_bf16(a[2], zf[0][kc], aL, 0, 0, 0); // c3 z1
            aL = __builtin_amdgcn_mfma_f32_32x32x16_bf16(a[0], zf[2][kc], aL, 0, 0, 0); // c1 z3
            aM = __builtin_amdgcn_mfma_f32_32x32x16_bf16(a[1], zf[0][kc], aM, 0, 0, 0); // c2 z1
            aM = __builtin_amdgcn_mfma_f32_32x32x16_bf16(a[0], zf[1][kc], aM, 0, 0, 0); // c1 z2
            aH = __builtin_amdgcn_mfma_f32_32x32x16_bf16(a[0], zf[0][kc], aH, 0, 0, 0); // c1 z1
        }
        // dist + running argmin. C/D: col=lane&31 (vector), row=(r&3)+8*(r>>2)+4g
        const int k0 = (grp << 9) + (ci << 5);
        #pragma unroll
        for (int j = 0; j < 4; ++j) {
            float4 c4 = *reinterpret_cast<const float4*>(&cc_lds[k0 + 8 * j + 4 * g]);
            const float cce[4] = {c4.x, c4.y, c4.z, c4.w};
            #pragma unroll
            for (int e = 0; e < 4; ++e) {
                const int r = 4 * j + e;
                float dot  = __fadd_rn(__fadd_rn(aL[r], aM[r]), aH[r]);
                float dist = __fsub_rn(__fadd_rn(zz, cce[e]),
                                       __fmul_rn(2.0f, dot));
                const int k = k0 + 8 * j + 4 * g + e;    // ascending within lane
                if (dist < bd) { bd = dist; bk = k; }
            }
        }
        asm volatile("s_waitcnt vmcnt(0)" ::: "memory");
        __syncthreads();
    }

    // ---- argmin merge: cross-half shuffle, then cross-group LDS atomicMin ----
    {
        unsigned long long pk =
            (((unsigned long long)__float_as_uint(bd)) << 32) | (unsigned)bk;
        unsigned long long other =
            (unsigned long long)__shfl_xor((long long)pk, 32, 64);
        if (other < pk) pk = other;
        if (g == 0) atomicMin(&best[vloc], pk);          // tie -> lower k
    }
    __syncthreads();

    // ---- epilogue: thread t < 128 <-> block-local vector t ----
    if (t < 128) {
        const int nn = (blk << 7) + t;
        const size_t zb2 = ((size_t)(nn >> 10) << 16) + (size_t)(nn & 1023);
        const int bkv = (int)(best[t] & 0xFFFFFFFFull);
        out[OFF_IDX + nn] = (float)bkv;
        atomicAdd(&hist[bkv], 1u);
        const float4* qrow = reinterpret_cast<const float4*>(cb + ((size_t)bkv << 6));
        float sq = 0.0f;
        #pragma unroll
        for (int j = 0; j < 16; ++j) {
            float4 q4 = qrow[j];
            const float qa[4] = {q4.x, q4.y, q4.z, q4.w};
            #pragma unroll
            for (int e = 0; e < 4; ++e) {
                const int d = 4 * j + e;
                out[zb2 + ((size_t)d << 10)] = qa[e];        // z_q_st == z_q
                float zx = ze[zb2 + ((size_t)d << 10)];
                float diff = __fsub_rn(qa[e], zx);
                sq = __fadd_rn(sq, __fmul_rn(diff, diff));
            }
        }
        #pragma unroll
        for (int off = 32; off > 0; off >>= 1) sq += __shfl_down(sq, off, 64);
        if (lane == 0) sred[t >> 6] = sq;
    }
    __syncthreads();
    if (t == 0) partial[blk] = sred[0] + sred[1];
}

// ---------------- fallback fp32 kernel (round-3, known-good) ----------------
__global__ __launch_bounds__(512, 4) void vq_main_fb(const float* __restrict__ ze,
                                                     const float* __restrict__ cb,
                                                     const float* __restrict__ cc,
                                                     unsigned* __restrict__ hist,
                                                     float* __restrict__ partial,
                                                     float* __restrict__ out) {
    const int lane = threadIdx.x & 63;
    const int w = __builtin_amdgcn_readfirstlane(threadIdx.x >> 6);
    const int n  = blockIdx.x * 64 + lane;
    const int b  = n >> 10;
    const int hw = n & 1023;
    const size_t zbase = ((size_t)b << 16) + (size_t)hw;
    float z[64];
    #pragma unroll
    for (int d = 0; d < 64; ++d) z[d] = ze[zbase + ((size_t)d << 10)];
    float zz = 0.0f;
    #pragma unroll
    for (int d = 0; d < 64; ++d) zz = __fadd_rn(zz, __fmul_rn(z[d], z[d]));
    float best = INFINITY; int bestk = 0;
    const int k0 = w << 7;
    for (int kk = 0; kk < 128; ++kk) {
        const int k = k0 + kk;
        const float4* crow = reinterpret_cast<const float4*>(cb + (k << 6));
        float p[4] = {0.0f, 0.0f, 0.0f, 0.0f};
        #pragma unroll
        for (int j = 0; j < 16; ++j) {
            float4 c4 = crow[j];
            p[j & 3] = fmaf(z[4*j + 0], c4.x, p[j & 3]);
            p[j & 3] = fmaf(z[4*j + 1], c4.y, p[j & 3]);
            p[j & 3] = fmaf(z[4*j + 2], c4.z, p[j & 3]);
            p[j & 3] = fmaf(z[4*j + 3], c4.w, p[j & 3]);
        }
        float dot  = __fadd_rn(__fadd_rn(p[0], p[1]), __fadd_rn(p[2], p[3]));
        float dist = __fsub_rn(__fadd_rn(zz, cc[k]), __fmul_rn(2.0f, dot));
        if (dist < best) { best = dist; bestk = k; }
    }
    __shared__ float s_best[7][64];
    __shared__ int   s_bk[7][64];
    if (w > 0) { s_best[w - 1][lane] = best; s_bk[w - 1][lane] = bestk; }
    __syncthreads();
    if (w == 0) {
        #pragma unroll
        for (int i = 0; i < 7; ++i) {
            float b2 = s_best[i][lane]; int k2 = s_bk[i][lane];
            if (b2 < best) { best = b2; bestk = k2; }
        }
        const float4* qrow = reinterpret_cast<const float4*>(cb + (bestk << 6));
        float sq = 0.0f;
        #pragma unroll
        for (int j = 0; j < 16; ++j) {
            float4 q4 = qrow[j];
            const float q[4] = {q4.x, q4.y, q4.z, q4.w};
            #pragma unroll
            for (int e = 0; e < 4; ++e) {
                int d = 4*j + e;
                out[zbase + ((size_t)d << 10)] = q[e];
                float diff = __fsub_rn(q[e], z[d]);
                sq = __fadd_rn(sq, __fmul_rn(diff, diff));
            }
        }
        out[OFF_IDX + n] = (float)bestk;
        atomicAdd(&hist[bestk], 1u);
        #pragma unroll
        for (int off = 32; off > 0; off >>= 1) sq += __shfl_down(sq, off, 64);
        if (lane == 0) partial[blockIdx.x] = sq;
    }
}

// ---------------- finalize ----------------
__global__ __launch_bounds__(256) void vq_fin(const float* __restrict__ partial,
                                              const unsigned* __restrict__ hist,
                                              float* __restrict__ out, int nb) {
    const int t = threadIdx.x;
    const int wid = t >> 6, lane = t & 63;
    __shared__ float s_loss[4], s_ent[4], s_nz[4];
    float v = 0.0f, ent = 0.0f, nz = 0.0f;
    for (int i = t; i < nb; i += 256) v += partial[i];
    #pragma unroll
    for (int i = 0; i < 4; ++i) {
        unsigned c = hist[t + 256 * i];
        float p = (float)c * (1.0f / 65536.0f);
        ent += p * logf(p + 1e-10f);
        if (c > 0u) nz += 1.0f;
    }
    #pragma unroll
    for (int off = 32; off > 0; off >>= 1) {
        v   += __shfl_down(v,   off, 64);
        ent += __shfl_down(ent, off, 64);
        nz  += __shfl_down(nz,  off, 64);
    }
    if (lane == 0) { s_loss[wid] = v; s_ent[wid] = ent; s_nz[wid] = nz; }
    __syncthreads();
    if (t == 0) {
        float S  = (s_loss[0] + s_loss[1]) + (s_loss[2] + s_loss[3]);
        float vq = S * (1.0f / 4194304.0f);
        out[OFF_VQLOSS] = vq;
        out[OFF_COMMIT] = 0.25f * vq;
        float E  = (s_ent[0] + s_ent[1]) + (s_ent[2] + s_ent[3]);
        float NZ = (s_nz[0] + s_nz[1]) + (s_nz[2] + s_nz[3]);
        out[OFF_USAGE] = NZ * (1.0f / 1024.0f);
        out[OFF_PERP]  = expf(-E);
    }
}

extern "C" void kernel_launch(void* const* d_in, const int* in_sizes, int n_in,
                              void* d_out, int out_size, void* d_ws, size_t ws_size,
                              hipStream_t stream) {
    const float* ze = (const float*)d_in[0];
    const float* cb = (const float*)d_in[1];
    float*    out  = (float*)d_out;
    float*    ws_f = (float*)d_ws;
    unsigned* ws_u = (unsigned*)d_ws;
    unsigned long long* cbs8 =
        (unsigned long long*)((char*)d_ws + CBS_BYTE_OFF);

    const int use_mfma = (ws_size >= (size_t)WS_REQUIRED);

    vq_init<<<dim3(4), dim3(256), 0, stream>>>(cb, ws_f, ws_u, cbs8, use_mfma);
    if (use_mfma) {
        vq_main<<<dim3(512), dim3(512), 0, stream>>>(ze, cb, ws_f, cbs8,
                                                     ws_u + 1024, ws_f + 2048, out);
        vq_fin<<<dim3(1), dim3(256), 0, stream>>>(ws_f + 2048, ws_u + 1024, out, 512);
    } else {
        vq_main_fb<<<dim3(1024), dim3(512), 0, stream>>>(ze, cb, ws_f, ws_u + 1024,
                                                         ws_f + 2048, out);
        vq_fin<<<dim3(1), dim3(256), 0, stream>>>(ws_f + 2048, ws_u + 1024, out, 1024);
    }
}